// Round 14
// baseline (345.662 us; speedup 1.0000x reference)
//
#include <hip/hip_runtime.h>
#include <hip/hip_cooperative_groups.h>

namespace cg = cooperative_groups;

// EmbGCN: B=64, N=2048, C_IN=C_OUT=32, D=16, K=2
// Primary: ONE cooperative launch, 3 phases with grid.sync().
// Round-13 failed with absmax=240 ~= max|ref| => suspected SILENT cooperative
// launch failure (return code unchecked; d_out stayed zero). This round: check
// the return code and FALL BACK to the proven 3-launch path (round-7, passed
// at 137.8us) if the cooperative launch is rejected. Deterministic either way.
// ws: A[2048*2048] f16 | xT[2048][2048] f16 (16.8MB)

#define NN 2048
#define NB 64
#define CI 32
#define CO 32
#define DD 16

typedef _Float16 half8 __attribute__((ext_vector_type(8)));
typedef __attribute__((ext_vector_type(4))) float f32x4;

#define GLOAD16(gp, lp) __builtin_amdgcn_global_load_lds(                 \
    (const __attribute__((address_space(1))) void*)(gp),                  \
    (__attribute__((address_space(3))) void*)(lp), 16, 0, 0)

// ======================= device helpers (shared bodies) =====================

__device__ __forceinline__ void adj_row_body(const float* __restrict__ E,
                                             _Float16* __restrict__ A,
                                             float* row, float* redmax,
                                             float* redsum, int n, int tid)
{
    const float4* __restrict__ E4 = (const float4*)E;
    const float4 e0 = E4[n * 4 + 0], e1 = E4[n * 4 + 1];
    const float4 e2 = E4[n * 4 + 2], e3 = E4[n * 4 + 3];
    float lmax = 0.0f;
    #pragma unroll
    for (int k = 0; k < 8; ++k) {
        const int m = tid + k * 256;
        const float4 f0 = E4[m * 4 + 0], f1 = E4[m * 4 + 1];
        const float4 f2 = E4[m * 4 + 2], f3 = E4[m * 4 + 3];
        float dot = e0.x * f0.x + e0.y * f0.y + e0.z * f0.z + e0.w * f0.w;
        dot += e1.x * f1.x + e1.y * f1.y + e1.z * f1.z + e1.w * f1.w;
        dot += e2.x * f2.x + e2.y * f2.y + e2.z * f2.z + e2.w * f2.w;
        dot += e3.x * f3.x + e3.y * f3.y + e3.z * f3.z + e3.w * f3.w;
        dot = fmaxf(dot, 0.0f);
        row[m] = dot;
        lmax = fmaxf(lmax, dot);
    }
    #pragma unroll
    for (int off = 32; off > 0; off >>= 1)
        lmax = fmaxf(lmax, __shfl_down(lmax, off, 64));
    if ((tid & 63) == 0) redmax[tid >> 6] = lmax;
    __syncthreads();
    const float gmax = fmaxf(fmaxf(redmax[0], redmax[1]),
                             fmaxf(redmax[2], redmax[3]));
    float lsum = 0.0f;
    #pragma unroll
    for (int k = 0; k < 8; ++k) {
        const int m = tid + k * 256;
        const float v = __expf(row[m] - gmax);
        row[m] = v;
        lsum += v;
    }
    #pragma unroll
    for (int off = 32; off > 0; off >>= 1)
        lsum += __shfl_down(lsum, off, 64);
    if ((tid & 63) == 0) redsum[tid >> 6] = lsum;
    __syncthreads();
    const float inv = 1.0f / (redsum[0] + redsum[1] + redsum[2] + redsum[3]);
    #pragma unroll
    for (int k = 0; k < 8; ++k) {
        const int m = tid + k * 256;
        A[(size_t)n * NN + m] = (_Float16)(row[m] * inv);
    }
}

__device__ __forceinline__ void xT_tile_body(const float* __restrict__ x,
                                             _Float16* __restrict__ xT,
                                             float (*tile)[33], int n, int tid)
{
    const int b = n >> 5, m0 = (n & 31) * 64;
    #pragma unroll
    for (int k = 0; k < 2; ++k) {
        const int idx = tid + k * 256;
        const int rr = idx >> 3, q = idx & 7;
        float4 v = *(const float4*)&x[((size_t)b * NN + m0 + rr) * CI + q * 4];
        tile[rr][q * 4 + 0] = v.x; tile[rr][q * 4 + 1] = v.y;
        tile[rr][q * 4 + 2] = v.z; tile[rr][q * 4 + 3] = v.w;
    }
    __syncthreads();
    const int c = tid >> 3, m8 = (tid & 7) * 8;
    _Float16 o[8];
    #pragma unroll
    for (int e = 0; e < 8; ++e) o[e] = (_Float16)tile[m8 + e][c];
    *(uint4*)&xT[((size_t)b * CI + c) * NN + m0 + m8] = *(uint4*)o;
}

__device__ __forceinline__ void gemm_tile_body(const _Float16* __restrict__ A,
                                               const _Float16* __restrict__ xT,
                                               float* __restrict__ agg,
                                               unsigned char* sm,
                                               int n0, int j0, int tid)
{
    const int lane = tid & 63;
    const int w = tid >> 6;
    const int wr = w >> 1, wc = w & 1;

    int soffA[2]; size_t gA[2];
    #pragma unroll
    for (int i = 0; i < 2; ++i) {
        const int off = i * 4096 + tid * 16;
        const int row = off >> 7, cb = off & 127;
        const int mm = (cb ^ ((row & 7) << 4)) >> 1;
        soffA[i] = off;
        gA[i] = (size_t)(n0 + row) * NN + mm;
    }
    int soffX[4]; size_t gX[4];
    #pragma unroll
    for (int i = 0; i < 4; ++i) {
        const int off = i * 4096 + tid * 16;
        const int row = off >> 7, cb = off & 127;
        const int mm = (cb ^ ((row & 7) << 4)) >> 1;
        soffX[i] = 8192 + off;
        gX[i] = (size_t)(j0 + row) * NN + mm;
    }

    const int l15 = lane & 15, lk = lane >> 4;
    const int sw = (lane & 7) << 4;
    int cbs[2];
    cbs[0] = (lk << 4) ^ sw;
    cbs[1] = (64 + (lk << 4)) ^ sw;
    int offA[2][2], offX[4][2];
    #pragma unroll
    for (int fm = 0; fm < 2; ++fm) {
        const int rr = wr * 32 + fm * 16 + l15;
        #pragma unroll
        for (int s = 0; s < 2; ++s)
            offA[fm][s] = (rr << 7) + cbs[s];
    }
    #pragma unroll
    for (int fj = 0; fj < 4; ++fj) {
        const int rr = wc * 64 + fj * 16 + l15;
        #pragma unroll
        for (int s = 0; s < 2; ++s)
            offX[fj][s] = 8192 + (rr << 7) + cbs[s];
    }

    f32x4 acc[2][4];
    #pragma unroll
    for (int fm = 0; fm < 2; ++fm)
        #pragma unroll
        for (int fj = 0; fj < 4; ++fj) acc[fm][fj] = (f32x4)0.0f;

    #pragma unroll
    for (int i = 0; i < 2; ++i)
        GLOAD16(A + gA[i], sm + soffA[i]);
    #pragma unroll
    for (int i = 0; i < 4; ++i)
        GLOAD16(xT + gX[i], sm + soffX[i]);
    __syncthreads();

    int buf = 0;
    for (int ks = 0; ks < NN / 64; ++ks) {
        const int nb = buf ^ 1;
        if (ks != NN / 64 - 1) {
            const size_t adv = (size_t)(ks + 1) * 64;
            #pragma unroll
            for (int i = 0; i < 2; ++i)
                GLOAD16(A + gA[i] + adv, sm + nb * 24576 + soffA[i]);
            #pragma unroll
            for (int i = 0; i < 4; ++i)
                GLOAD16(xT + gX[i] + adv, sm + nb * 24576 + soffX[i]);
        }
        const unsigned char* Bp2 = sm + buf * 24576;
        half8 av[2][2], xv[4][2];
        #pragma unroll
        for (int fm = 0; fm < 2; ++fm)
            #pragma unroll
            for (int s = 0; s < 2; ++s)
                av[fm][s] = *(const half8*)(Bp2 + offA[fm][s]);
        #pragma unroll
        for (int fj = 0; fj < 4; ++fj)
            #pragma unroll
            for (int s = 0; s < 2; ++s)
                xv[fj][s] = *(const half8*)(Bp2 + offX[fj][s]);

        #pragma unroll
        for (int s = 0; s < 2; ++s)
            #pragma unroll
            for (int fm = 0; fm < 2; ++fm)
                #pragma unroll
                for (int fj = 0; fj < 4; ++fj)
                    acc[fm][fj] = __builtin_amdgcn_mfma_f32_16x16x32_f16(
                        av[fm][s], xv[fj][s], acc[fm][fj], 0, 0, 0);
        __syncthreads();
        buf = nb;
    }

    #pragma unroll
    for (int fm = 0; fm < 2; ++fm)
        #pragma unroll
        for (int fj = 0; fj < 4; ++fj) {
            const int nbase = n0 + wr * 32 + fm * 16 + lk * 4;
            const int j = j0 + wc * 64 + fj * 16 + l15;
            const int b = j >> 5, c = j & 31;
            #pragma unroll
            for (int rr = 0; rr < 4; ++rr)
                agg[((size_t)b * NN + nbase + rr) * CI + c] = acc[fm][fj][rr];
        }
}

__device__ __forceinline__ void outw_body(const float* __restrict__ E,
                                          const float* __restrict__ Wp,
                                          const float* __restrict__ Bp,
                                          const float* __restrict__ x,
                                          float* __restrict__ out,
                                          float* W, float (*Xs)[CI],
                                          float (*Gs)[CI], int n, int tid)
{
    {
        const int b = tid >> 3, q = (tid & 7) * 4;
        const int b2 = (tid + 256) >> 3;
        GLOAD16(x + ((size_t)b * NN + n) * CI + q,    (char*)Xs + tid * 16);
        GLOAD16(x + ((size_t)b2 * NN + n) * CI + q,   (char*)Xs + 4096 + tid * 16);
        GLOAD16(out + ((size_t)b * NN + n) * CI + q,  (char*)Gs + tid * 16);
        GLOAD16(out + ((size_t)b2 * NN + n) * CI + q, (char*)Gs + 4096 + tid * 16);
    }

    float e[DD];
    #pragma unroll
    for (int d = 0; d < DD; ++d) e[d] = E[n * DD + d];

    {
        const float4* __restrict__ Wp4 = (const float4*)Wp;  // [16][512]
        float4 a0 = make_float4(0.f, 0.f, 0.f, 0.f);
        float4 a1 = make_float4(0.f, 0.f, 0.f, 0.f);
        #pragma unroll
        for (int d = 0; d < DD; ++d) {
            const float4 w0v = Wp4[d * 512 + tid];
            const float4 w1v = Wp4[d * 512 + 256 + tid];
            const float c = e[d];
            a0.x = fmaf(c, w0v.x, a0.x); a0.y = fmaf(c, w0v.y, a0.y);
            a0.z = fmaf(c, w0v.z, a0.z); a0.w = fmaf(c, w0v.w, a0.w);
            a1.x = fmaf(c, w1v.x, a1.x); a1.y = fmaf(c, w1v.y, a1.y);
            a1.z = fmaf(c, w1v.z, a1.z); a1.w = fmaf(c, w1v.w, a1.w);
        }
        *(float4*)&W[tid * 4] = a0;
        *(float4*)&W[1024 + tid * 4] = a1;
    }
    __syncthreads();

    const int o  = tid & 31;
    const int bb = tid >> 5;

    float bias = 0.0f;
    #pragma unroll
    for (int d = 0; d < DD; ++d) bias = fmaf(e[d], Bp[d * CO + o], bias);

    float w0[CI], w1[CI];
    #pragma unroll
    for (int i = 0; i < CI; ++i) {
        w0[i] = W[i * 32 + o];
        w1[i] = W[1024 + i * 32 + o];
    }

    #pragma unroll
    for (int j = 0; j < 8; ++j) {
        const int b = bb + 8 * j;
        float s = bias;
        #pragma unroll
        for (int iq = 0; iq < 8; ++iq) {
            const float4 xq = *(const float4*)&Xs[b][iq * 4];
            const float4 gq = *(const float4*)&Gs[b][iq * 4];
            s = fmaf(xq.x, w0[iq * 4 + 0], s);
            s = fmaf(xq.y, w0[iq * 4 + 1], s);
            s = fmaf(xq.z, w0[iq * 4 + 2], s);
            s = fmaf(xq.w, w0[iq * 4 + 3], s);
            s = fmaf(gq.x, w1[iq * 4 + 0], s);
            s = fmaf(gq.y, w1[iq * 4 + 1], s);
            s = fmaf(gq.z, w1[iq * 4 + 2], s);
            s = fmaf(gq.w, w1[iq * 4 + 3], s);
        }
        out[((size_t)b * NN + n) * CO + o] = s;
    }
}

// ======================= fallback kernels (round-7 proven) ==================

__global__ __launch_bounds__(256) void adjxT_kernel(const float* __restrict__ E,
                                                    const float* __restrict__ x,
                                                    _Float16* __restrict__ A,
                                                    _Float16* __restrict__ xT)
{
    __shared__ float tile[64][33];
    __shared__ float row[NN];
    __shared__ float redmax[4];
    __shared__ float redsum[4];
    xT_tile_body(x, xT, tile, blockIdx.x, threadIdx.x);
    adj_row_body(E, A, row, redmax, redsum, blockIdx.x, threadIdx.x);
}

__global__ __launch_bounds__(256, 2) void agg_mfma(const _Float16* __restrict__ A,
                                                   const _Float16* __restrict__ xT,
                                                   float* __restrict__ agg)
{
    const int wg = blockIdx.x;
    const int logical = (wg & 7) * 64 + (wg >> 3);
    __shared__ __align__(16) unsigned char sm[49152];
    gemm_tile_body(A, xT, agg, sm, (logical & 31) * 64, (logical >> 5) * 128,
                   threadIdx.x);
}

__global__ __launch_bounds__(256) void outw_kernel(const float* __restrict__ E,
                                                   const float* __restrict__ Wp,
                                                   const float* __restrict__ Bp,
                                                   const float* __restrict__ x,
                                                   float* __restrict__ out)
{
    __shared__ __align__(16) float W[2 * CI * CO];
    __shared__ __align__(16) float Xs[NB][CI];
    __shared__ __align__(16) float Gs[NB][CI];
    outw_body(E, Wp, Bp, x, out, W, Xs, Gs, blockIdx.x, threadIdx.x);
}

// ======================= cooperative fused kernel ===========================

__global__ __launch_bounds__(256, 2) void fused_kernel(
    const float* __restrict__ E, const float* __restrict__ x,
    const float* __restrict__ Wp, const float* __restrict__ Bp,
    float* __restrict__ out, _Float16* __restrict__ A,
    _Float16* __restrict__ xT)
{
    cg::grid_group grid = cg::this_grid();
    const int tid = threadIdx.x;
    const int blk = blockIdx.x;

    __shared__ __align__(16) unsigned char sm[49152];

    // Phase 1: 4 adj rows + 4 xT tiles per block
    {
        float* row = (float*)sm;
        float (*tile)[33] = (float(*)[33])(sm + 8192);
        float* redmax = (float*)(sm + 16640);
        float* redsum = (float*)(sm + 16656);
        for (int r = 0; r < 4; ++r) {
            const int n = blk * 4 + r;
            xT_tile_body(x, xT, tile, n, tid);
            adj_row_body(E, A, row, redmax, redsum, n, tid);
            __syncthreads();
        }
    }
    __threadfence();
    grid.sync();

    // Phase 2: GEMM tile
    {
        const int logical = (blk & 7) * 64 + (blk >> 3);
        gemm_tile_body(A, xT, out, sm, (logical & 31) * 64,
                       (logical >> 5) * 128, tid);
    }
    __threadfence();
    grid.sync();

    // Phase 3: 4 outw nodes per block
    {
        float* W = (float*)sm;
        float (*Xs)[CI] = (float(*)[CI])(sm + 8192);
        float (*Gs)[CI] = (float(*)[CI])(sm + 16384);
        for (int r = 0; r < 4; ++r) {
            outw_body(E, Wp, Bp, x, out, W, Xs, Gs, blk * 4 + r, tid);
            __syncthreads();
        }
    }
}

extern "C" void kernel_launch(void* const* d_in, const int* in_sizes, int n_in,
                              void* d_out, int out_size, void* d_ws, size_t ws_size,
                              hipStream_t stream)
{
    const float* x  = (const float*)d_in[0];   // [64,2048,32]
    const float* E  = (const float*)d_in[1];   // [2048,16]
    const float* Wp = (const float*)d_in[2];   // [16,2,32,32]
    const float* Bp = (const float*)d_in[3];   // [16,32]
    float* out = (float*)d_out;                // [64,2048,32]

    _Float16* A  = (_Float16*)d_ws;            // 2048*2048 f16
    _Float16* xT = A + (size_t)NN * NN;        // 2048*2048 f16

    void* args[] = {(void*)&E, (void*)&x, (void*)&Wp, (void*)&Bp,
                    (void*)&out, (void*)&A, (void*)&xT};
    hipError_t err = hipLaunchCooperativeKernel((void*)fused_kernel, dim3(512),
                                                dim3(256), args, 0, stream);
    if (err != hipSuccess) {
        // deterministic fallback: proven 3-launch path (round-7, 137.8us)
        (void)hipGetLastError();   // clear sticky error
        adjxT_kernel<<<NN, 256, 0, stream>>>(E, x, A, xT);
        agg_mfma<<<512, 256, 0, stream>>>(A, xT, out);
        outw_kernel<<<NN, 256, 0, stream>>>(E, Wp, Bp, x, out);
    }
}